// Round 1
// baseline (495.211 us; speedup 1.0000x reference)
//
#include <hip/hip_runtime.h>

#define HW    16384
#define BB    8
#define KK    19
#define CC    512
#define NS    16           // s-splits per (b, ctile)
#define SCHUNK (HW / NS)   // 1024

// ---------------- Stage 1: row softmax over spatial dim ----------------
// grid = B*K blocks, 256 threads. Row (16384 floats) held in registers
// (16 float4 per thread). Two block reductions (max, sum).
__global__ __launch_bounds__(256) void softmax_rows(const float* __restrict__ probs,
                                                    float* __restrict__ w) {
    const int row = blockIdx.x;                      // b*K + k
    const float4* p = reinterpret_cast<const float4*>(probs + (size_t)row * HW);
    float4* wr = reinterpret_cast<float4*>(w + (size_t)row * HW);
    const int tid = threadIdx.x;

    __shared__ float sred[4];

    float4 v[16];
    float m = -INFINITY;
    #pragma unroll
    for (int i = 0; i < 16; ++i) {
        v[i] = p[tid + i * 256];
        m = fmaxf(m, fmaxf(fmaxf(v[i].x, v[i].y), fmaxf(v[i].z, v[i].w)));
    }
    // block-reduce max
    #pragma unroll
    for (int off = 32; off; off >>= 1) m = fmaxf(m, __shfl_xor(m, off));
    if ((tid & 63) == 0) sred[tid >> 6] = m;
    __syncthreads();
    m = fmaxf(fmaxf(sred[0], sred[1]), fmaxf(sred[2], sred[3]));
    __syncthreads();

    const float l2e = 1.44269504088896340736f;
    float s = 0.f;
    #pragma unroll
    for (int i = 0; i < 16; ++i) {
        v[i].x = exp2f((v[i].x - m) * l2e);
        v[i].y = exp2f((v[i].y - m) * l2e);
        v[i].z = exp2f((v[i].z - m) * l2e);
        v[i].w = exp2f((v[i].w - m) * l2e);
        s += (v[i].x + v[i].y) + (v[i].z + v[i].w);
    }
    // block-reduce sum
    #pragma unroll
    for (int off = 32; off; off >>= 1) s += __shfl_xor(s, off);
    if ((tid & 63) == 0) sred[tid >> 6] = s;
    __syncthreads();
    s = (sred[0] + sred[1]) + (sred[2] + sred[3]);
    const float inv = 1.0f / s;

    #pragma unroll
    for (int i = 0; i < 16; ++i) {
        float4 o;
        o.x = v[i].x * inv; o.y = v[i].y * inv;
        o.z = v[i].z * inv; o.w = v[i].w * inv;
        wr[tid + i * 256] = o;
    }
}

// ---------------- Stage 2: ctx[b,c,k] = sum_s w[b,k,s] * f[b,c,s] ------
// 256 threads: s_idx = tid&15 (16 lanes stride s as float4), cg = tid>>4
// (16 channel groups x 4 channels each = 64 channels per block).
// Each thread: acc[19][4] register tile; feats global->reg (read once),
// weights via L1 (high temporal reuse). Shuffle-reduce over 16 s-lanes,
// atomicAdd into zeroed output.
__global__ __launch_bounds__(256) void gather_ctx(const float* __restrict__ feats,
                                                  const float* __restrict__ w,
                                                  float* __restrict__ out) {
    const int bid   = blockIdx.x;
    const int ns    = bid & (NS - 1);
    const int ctile = (bid >> 4) & 7;      // C/64 = 8 tiles
    const int b     = bid >> 7;
    const int tid   = threadIdx.x;
    const int s_idx = tid & 15;
    const int cg    = tid >> 4;
    const int c0    = ctile * 64 + cg * 4;

    const float4* f0 = reinterpret_cast<const float4*>(feats + ((size_t)(b * CC + c0)) * HW);
    const float4* w0 = reinterpret_cast<const float4*>(w + ((size_t)b * KK) * HW);
    const int s4_0 = (ns * SCHUNK) >> 2;   // float4 index of chunk start

    float acc[KK][4];
    #pragma unroll
    for (int k = 0; k < KK; ++k)
        #pragma unroll
        for (int j = 0; j < 4; ++j) acc[k][j] = 0.f;

    #pragma unroll 1
    for (int it = 0; it < SCHUNK / 64; ++it) {   // 16 iters
        const int s4 = s4_0 + it * 16 + s_idx;
        float4 f[4];
        #pragma unroll
        for (int j = 0; j < 4; ++j) f[j] = f0[(size_t)j * (HW / 4) + s4];
        #pragma unroll
        for (int k = 0; k < KK; ++k) {
            const float4 ww = w0[(size_t)k * (HW / 4) + s4];
            #pragma unroll
            for (int j = 0; j < 4; ++j) {
                acc[k][j] += ww.x * f[j].x + ww.y * f[j].y
                           + ww.z * f[j].z + ww.w * f[j].w;
            }
        }
    }

    // reduce across the 16 s-lanes (xor masks stay inside the 16-lane group)
    #pragma unroll
    for (int k = 0; k < KK; ++k)
        #pragma unroll
        for (int j = 0; j < 4; ++j) {
            float v = acc[k][j];
            v += __shfl_xor(v, 1);
            v += __shfl_xor(v, 2);
            v += __shfl_xor(v, 4);
            v += __shfl_xor(v, 8);
            acc[k][j] = v;
        }

    if (s_idx == 0) {
        #pragma unroll
        for (int j = 0; j < 4; ++j)
            #pragma unroll
            for (int k = 0; k < KK; ++k)
                atomicAdd(&out[((size_t)(b * CC + c0 + j)) * KK + k], acc[k][j]);
    }
}

extern "C" void kernel_launch(void* const* d_in, const int* in_sizes, int n_in,
                              void* d_out, int out_size, void* d_ws, size_t ws_size,
                              hipStream_t stream) {
    const float* feats = (const float*)d_in[0];   // (8, 512, 128, 128)
    const float* probs = (const float*)d_in[1];   // (8, 19, 128, 128)
    float* out = (float*)d_out;                   // (8, 512, 19, 1)
    float* w   = (float*)d_ws;                    // B*K*HW floats = ~10 MB

    // output is re-poisoned before every timed call -> zero it (atomicAdd target)
    hipMemsetAsync(d_out, 0, (size_t)out_size * sizeof(float), stream);

    softmax_rows<<<BB * KK, 256, 0, stream>>>(probs, w);

    gather_ctx<<<BB * (CC / 64) * NS, 256, 0, stream>>>(feats, w, out);
}